// Round 2
// baseline (43054.269 us; speedup 1.0000x reference)
//
#include <hip/hip_runtime.h>
#include <cstdint>
#include <cstddef>

#define V_SZ 32000
#define H_SZ 1024
#define T_SZ 512
#define B_SZ 64

typedef short short8 __attribute__((ext_vector_type(8)));
typedef float f32x4 __attribute__((ext_vector_type(4)));

__device__ __forceinline__ short f2bf(float f) {
  union { float f; unsigned u; } v; v.f = f;
  unsigned r = (v.u + 0x7fffu + ((v.u >> 16) & 1u)) >> 16;  // RNE, inputs finite
  return (short)r;
}

// embT[v][h] = bf16(emb_w[h][v] + emb_b[h])  -- tiled transpose, both sides coalesced
__global__ __launch_bounds__(256) void k_embT(const float* __restrict__ emb_w,
                                              const float* __restrict__ emb_b,
                                              short* __restrict__ embT) {
  __shared__ float tile[64][65];
  const int v0 = blockIdx.x * 64, h0 = blockIdx.y * 64;
  const int c = threadIdx.x & 63, rg = threadIdx.x >> 6;
#pragma unroll
  for (int p = 0; p < 16; ++p) {
    int r = rg * 16 + p;
    tile[r][c] = emb_w[(size_t)(h0 + r) * V_SZ + v0 + c];
  }
  __syncthreads();
  const float bias = emb_b[h0 + c];
#pragma unroll
  for (int p = 0; p < 16; ++p) {
    int vr = rg * 16 + p;
    embT[(size_t)(v0 + vr) * H_SZ + h0 + c] = f2bf(tile[c][vr] + bias);
  }
}

__global__ __launch_bounds__(256) void k_cast(const float* __restrict__ s,
                                              short* __restrict__ d, int n) {
  for (int i = blockIdx.x * 256 + threadIdx.x; i < n; i += gridDim.x * 256)
    d[i] = f2bf(s[i]);
}

__global__ __launch_bounds__(256) void k_copy(const float* __restrict__ s,
                                              float* __restrict__ d, int n) {
  for (int i = blockIdx.x * 256 + threadIdx.x; i < n; i += gridDim.x * 256)
    d[i] = s[i];
}

// Persistent bidirectional LSTM. 256 blocks x 512 threads, 1 block/CU.
// block: d = blockIdx>>7, n0 = (blockIdx&127)*8 output cols (x4 gates = 32 W-rows).
// wave w: mt = w>>2 (batch 32-half), ks = w&3 (K quarter, strided mod 4).
// B-fragments (weights) live in 128 VGPRs for all 512 steps. c-state in a register.
__global__ __launch_bounds__(512, 2) void k_persist(
    const int* __restrict__ tokens, const short* __restrict__ embT,
    const short* __restrict__ Wbf, const float* __restrict__ biasws,
    short* __restrict__ hbf, unsigned* __restrict__ bar,
    float* __restrict__ out) {
  __shared__ __align__(16) short Abuf[2][16384];   // ring-2: [64 rows][256 k] each
  __shared__ float P_lds[4][64][36];               // [ks][b][32 cols] pad->stride 36

  const int tid = threadIdx.x;
  const int lane = tid & 63, w = tid >> 6;
  const int l15 = lane & 15, l4 = lane >> 4;
  const int d = (int)(blockIdx.x >> 7);
  const int n0 = (int)(blockIdx.x & 127) << 3;
  const int mt = w >> 2, ks = w & 3;

  // staging map: thread owns row row_st, 64 contiguous bytes at koff*2
  const int row_st = tid >> 3;
  const int koff = (tid & 7) * 32;                 // elements within 256-chunk
  const int swzst = (row_st & 7) << 4;

  // ---- load step-invariant B fragments into registers ----
  short8 Bf[16][2];
#pragma unroll
  for (int j = 0; j < 16; ++j)
#pragma unroll
    for (int nt = 0; nt < 2; ++nt) {
      int row32 = nt * 16 + l15;
      size_t grow = (size_t)((d * 4 + (row32 >> 3)) * 1024 + n0 + (row32 & 7));
      Bf[j][nt] = *(const short8*)(Wbf + grow * 2048 + (j * 4 + ks) * 32 + l4 * 8);
    }

  // ---- gate-phase constants: thread owns (b=tid>>3, col=n0+(tid&7)) ----
  const int gb = tid >> 3, gnn = tid & 7, gcol = n0 + gnn;
  float brg[4];
#pragma unroll
  for (int g4 = 0; g4 < 4; ++g4) brg[g4] = biasws[d * 4096 + g4 * 1024 + gcol];
  float c_reg = 0.f;

  unsigned* const cnt = bar + d * 32;  // per-dir counter, separate cachelines

  // preload x-chunk0 of step 0
  short8 pre0[4];
  {
    int tok = tokens[(d ? (T_SZ - 1) : 0) * B_SZ + row_st];
    const short* s = embT + (size_t)tok * 1024 + koff;
#pragma unroll
    for (int p = 0; p < 4; ++p) pre0[p] = *(const short8*)(s + p * 8);
  }

  for (int t = 0; t < T_SZ; ++t) {
    const int td = d ? (T_SZ - 1 - t) : t;
    const short* hsrc = hbf + ((t & 1) * 2 + d) * 65536;
    short* hdst = hbf + (((t + 1) & 1) * 2 + d) * 65536;

    // write preloaded chunk0 into slot 0
#pragma unroll
    for (int p = 0; p < 4; ++p)
      *(short8*)((char*)Abuf[0] + ((row_st * 512 + koff * 2 + p * 16) ^ swzst)) = pre0[p];
    __syncthreads();

    f32x4 acc[2][2] = {{{0,0,0,0},{0,0,0,0}},{{0,0,0,0},{0,0,0,0}}};

#pragma unroll
    for (int c = 0; c < 8; ++c) {
      short8 nx[4];
      if (c < 7) {                      // issue-early load of chunk c+1
        int cn = c + 1;
        const short* s;
        if (cn < 4) {
          int tok = tokens[td * B_SZ + row_st];
          s = embT + (size_t)tok * 1024 + cn * 256 + koff;
        } else {
          s = hsrc + row_st * 1024 + (cn - 4) * 256 + koff;
        }
#pragma unroll
        for (int p = 0; p < 4; ++p) nx[p] = *(const short8*)(s + p * 8);
      }
      const char* base = (const char*)Abuf[c & 1];
#pragma unroll
      for (int j2 = 0; j2 < 2; ++j2) {
        const int j = c * 2 + j2;                       // static B index
        const int kc2 = ((j2 * 4 + ks) * 32 + l4 * 8) * 2;
#pragma unroll
        for (int ms = 0; ms < 2; ++ms) {
          int row = mt * 32 + ms * 16 + l15;
          short8 afr = *(const short8*)(base + ((row * 512 + kc2) ^ ((row & 7) << 4)));
#pragma unroll
          for (int ns = 0; ns < 2; ++ns)
            acc[ms][ns] = __builtin_amdgcn_mfma_f32_16x16x32_bf16(afr, Bf[j][ns],
                                                                  acc[ms][ns], 0, 0, 0);
        }
      }
      if (c < 7) {                      // write-late into the other slot
        char* wb = (char*)Abuf[(c + 1) & 1];
#pragma unroll
        for (int p = 0; p < 4; ++p)
          *(short8*)(wb + ((row_st * 512 + koff * 2 + p * 16) ^ swzst)) = nx[p];
      }
      __syncthreads();
    }

    // ---- K-split partial dump (C layout: b=(lane>>4)*4+i, col=lane&15) ----
#pragma unroll
    for (int ms = 0; ms < 2; ++ms)
#pragma unroll
      for (int ns = 0; ns < 2; ++ns)
#pragma unroll
        for (int i = 0; i < 4; ++i)
          P_lds[ks][mt * 32 + ms * 16 + l4 * 4 + i][ns * 16 + l15] = acc[ms][ns][i];
    __syncthreads();

    // ---- gate math + state update ----
    float pr[4];
#pragma unroll
    for (int g4 = 0; g4 < 4; ++g4) {
      float s = brg[g4];
#pragma unroll
      for (int q = 0; q < 4; ++q) s += P_lds[q][gb][g4 * 8 + gnn];
      pr[g4] = s;
    }
    float ig = 1.0f / (1.0f + expf(-pr[0]));
    float og = 1.0f / (1.0f + expf(-pr[1]));
    float fg = 1.0f / (1.0f + expf(-pr[2]));
    float cg = tanhf(pr[3]);
    c_reg = fg * c_reg + ig * cg;
    float hnew = og * tanhf(c_reg);
    hdst[gb * 1024 + gcol] = f2bf(hnew);
    size_t o = (size_t)(t * B_SZ + gb) * 2048 + (size_t)d * 1024 + gcol;
    out[o] = hnew;                     // hidden
    out[o + 67108864] = c_reg;         // cell (+T*B*2H)

    if (t < T_SZ - 1) {
      // arrive (release: orders the h stores before the count bump)
      __hip_atomic_fetch_add(cnt, 1u, __ATOMIC_RELEASE, __HIP_MEMORY_SCOPE_AGENT);
      // preload next step's x-chunk0 under the barrier wait (read-only data)
      {
        int tok = tokens[(d ? (T_SZ - 2 - t) : (t + 1)) * B_SZ + row_st];
        const short* s = embT + (size_t)tok * 1024 + koff;
#pragma unroll
        for (int p = 0; p < 4; ++p) pre0[p] = *(const short8*)(s + p * 8);
      }
      const unsigned target = (unsigned)(t + 1) * 65536u;  // 128 blk * 512 thr per dir
      while (__hip_atomic_load(cnt, __ATOMIC_RELAXED, __HIP_MEMORY_SCOPE_AGENT) < target)
        __builtin_amdgcn_s_sleep(2);
      (void)__hip_atomic_load(cnt, __ATOMIC_ACQUIRE, __HIP_MEMORY_SCOPE_AGENT);
    }
  }
}

extern "C" void kernel_launch(void* const* d_in, const int* in_sizes, int n_in,
                              void* d_out, int out_size, void* d_ws, size_t ws_size,
                              hipStream_t stream) {
  (void)in_sizes; (void)n_in; (void)out_size; (void)ws_size;
  const int* tokens  = (const int*)d_in[0];
  const float* emb_w = (const float*)d_in[1];
  const float* emb_b = (const float*)d_in[2];

  char* ws = (char*)d_ws;
  short* embT   = (short*)(ws);               // 65,536,000 B
  short* Wbf    = (short*)(ws + 65536000);    // 33,554,432 B
  float* biasws = (float*)(ws + 99090432);    //     32,768 B
  short* hbf    = (short*)(ws + 99123200);    //    524,288 B (2 phase x 2 dir x 64x1024)
  unsigned* bar = (unsigned*)(ws + 99647488); //        512 B

  hipMemsetAsync(ws + 99123200, 0, 524288 + 512, stream);

  k_embT<<<dim3(500, 16), 256, 0, stream>>>(emb_w, emb_b, embT);

  for (int d = 0; d < 2; ++d)
    for (int g = 0; g < 4; ++g) {
      const float* wsrc = (const float*)d_in[3 + d * 8 + g * 2];
      const float* bsrc = (const float*)d_in[4 + d * 8 + g * 2];
      k_cast<<<1024, 256, 0, stream>>>(wsrc, Wbf + (size_t)(d * 4 + g) * 1024 * 2048,
                                       1024 * 2048);
      k_copy<<<4, 256, 0, stream>>>(bsrc, biasws + (d * 4 + g) * 1024, 1024);
    }

  float* outp = (float*)d_out;
  void* kargs[] = {(void*)&tokens, (void*)&embT, (void*)&Wbf, (void*)&biasws,
                   (void*)&hbf, (void*)&bar, (void*)&outp};
  hipLaunchCooperativeKernel((const void*)k_persist, dim3(256), dim3(512), kargs, 0,
                             stream);
}

// Round 4
// 14502.573 us; speedup vs baseline: 2.9687x; 2.9687x over previous
//
#include <hip/hip_runtime.h>
#include <cstdint>
#include <cstddef>

#define V_SZ 32000
#define H_SZ 1024
#define T_SZ 512
#define B_SZ 64

typedef short short8 __attribute__((ext_vector_type(8)));
typedef float f32x4 __attribute__((ext_vector_type(4)));

__device__ __forceinline__ short f2bf(float f) {
  union { float f; unsigned u; } v; v.f = f;
  unsigned r = (v.u + 0x7fffu + ((v.u >> 16) & 1u)) >> 16;  // RNE, inputs finite
  return (short)r;
}

// embT[v][h] = bf16(emb_w[h][v] + emb_b[h])  -- tiled transpose, both sides coalesced
__global__ __launch_bounds__(256) void k_embT(const float* __restrict__ emb_w,
                                              const float* __restrict__ emb_b,
                                              short* __restrict__ embT) {
  __shared__ float tile[64][65];
  const int v0 = blockIdx.x * 64, h0 = blockIdx.y * 64;
  const int c = threadIdx.x & 63, rg = threadIdx.x >> 6;
#pragma unroll
  for (int p = 0; p < 16; ++p) {
    int r = rg * 16 + p;
    tile[r][c] = emb_w[(size_t)(h0 + r) * V_SZ + v0 + c];
  }
  __syncthreads();
  const float bias = emb_b[h0 + c];
#pragma unroll
  for (int p = 0; p < 16; ++p) {
    int vr = rg * 16 + p;
    embT[(size_t)(v0 + vr) * H_SZ + h0 + c] = f2bf(tile[c][vr] + bias);
  }
}

__global__ __launch_bounds__(256) void k_cast(const float* __restrict__ s,
                                              short* __restrict__ d, int n) {
  for (int i = blockIdx.x * 256 + threadIdx.x; i < n; i += gridDim.x * 256)
    d[i] = f2bf(s[i]);
}

__global__ __launch_bounds__(256) void k_copy(const float* __restrict__ s,
                                              float* __restrict__ d, int n) {
  for (int i = blockIdx.x * 256 + threadIdx.x; i < n; i += gridDim.x * 256)
    d[i] = s[i];
}

// Persistent bidirectional LSTM. 256 blocks x 512 threads, 1 block/CU.
// block: d = blockIdx>>7, n0 = (blockIdx&127)*8 output cols (x4 gates = 32 W-rows).
// wave w: mt = w>>2 (batch 32-half), ks = w&3 (K quarter, strided mod 4).
// B-fragments (weights) live in VGPRs for all 512 steps; c-state in a register.
// Grid barrier: ONE atomic arrival + ONE spinner per block per step.
__global__ __launch_bounds__(512, 2) void k_persist(
    const int* __restrict__ tokens, const short* __restrict__ embT,
    const short* __restrict__ Wbf, const float* __restrict__ biasws,
    short* __restrict__ hbf, unsigned* __restrict__ bar,
    float* __restrict__ out) {
  __shared__ __align__(16) short Abuf[2][16384];   // ring-2: [64 rows][256 k] each
  __shared__ float P_lds[4][64][36];               // [ks][b][32 cols] pad->stride 36

  const int tid = threadIdx.x;
  const int lane = tid & 63, w = tid >> 6;
  const int l15 = lane & 15, l4 = lane >> 4;
  const int d = (int)(blockIdx.x >> 7);
  const int n0 = (int)(blockIdx.x & 127) << 3;
  const int mt = w >> 2, ks = w & 3;

  // staging map: thread owns row row_st, 64 contiguous bytes at koff*2
  const int row_st = tid >> 3;
  const int koff = (tid & 7) * 32;                 // elements within 256-chunk
  const int swzst = (row_st & 7) << 4;

  // ---- load step-invariant B fragments into registers ----
  short8 Bf[16][2];
#pragma unroll
  for (int j = 0; j < 16; ++j)
#pragma unroll
    for (int nt = 0; nt < 2; ++nt) {
      int row32 = nt * 16 + l15;
      size_t grow = (size_t)((d * 4 + (row32 >> 3)) * 1024 + n0 + (row32 & 7));
      Bf[j][nt] = *(const short8*)(Wbf + grow * 2048 + (j * 4 + ks) * 32 + l4 * 8);
    }

  // ---- gate-phase constants: thread owns (b=tid>>3, col=n0+(tid&7)) ----
  const int gb = tid >> 3, gnn = tid & 7, gcol = n0 + gnn;
  float brg[4];
#pragma unroll
  for (int g4 = 0; g4 < 4; ++g4) brg[g4] = biasws[d * 4096 + g4 * 1024 + gcol];
  float c_reg = 0.f;
  float pend_h = 0.f;                               // deferred out-store values

  unsigned* const cnt = bar + d * 64;  // per-dir counter, 256B apart

  // preload x-chunk0 of step 0
  short8 pre0[4];
  {
    int tok = tokens[(d ? (T_SZ - 1) : 0) * B_SZ + row_st];
    const short* s = embT + (size_t)tok * 1024 + koff;
#pragma unroll
    for (int p = 0; p < 4; ++p) pre0[p] = *(const short8*)(s + p * 8);
  }

  for (int t = 0; t < T_SZ; ++t) {
    const int td = d ? (T_SZ - 1 - t) : t;
    const short* hsrc = hbf + ((t & 1) * 2 + d) * 65536;
    short* hdst = hbf + (((t + 1) & 1) * 2 + d) * 65536;

    // deferred out-stores for step t-1 (off the critical path: overlap staging)
    if (t > 0) {
      size_t o = (size_t)(((t - 1) * B_SZ + gb)) * 2048 + (size_t)d * 1024 + gcol;
      out[o] = pend_h;
      out[o + 67108864] = c_reg;
    }

    // write preloaded chunk0 into slot 0
#pragma unroll
    for (int p = 0; p < 4; ++p)
      *(short8*)((char*)Abuf[0] + ((row_st * 512 + koff * 2 + p * 16) ^ swzst)) = pre0[p];
    __syncthreads();

    f32x4 acc[2][2] = {{{0,0,0,0},{0,0,0,0}},{{0,0,0,0},{0,0,0,0}}};

#pragma unroll
    for (int c = 0; c < 8; ++c) {
      short8 nx[4];
      if (c < 7) {                      // issue-early load of chunk c+1
        int cn = c + 1;
        const short* s;
        if (cn < 4) {
          int tok = tokens[td * B_SZ + row_st];
          s = embT + (size_t)tok * 1024 + cn * 256 + koff;
        } else {
          s = hsrc + row_st * 1024 + (cn - 4) * 256 + koff;
        }
#pragma unroll
        for (int p = 0; p < 4; ++p) nx[p] = *(const short8*)(s + p * 8);
      }
      const char* base = (const char*)Abuf[c & 1];
#pragma unroll
      for (int j2 = 0; j2 < 2; ++j2) {
        const int j = c * 2 + j2;                       // static B index
        const int kc2 = ((j2 * 4 + ks) * 32 + l4 * 8) * 2;
#pragma unroll
        for (int ms = 0; ms < 2; ++ms) {
          int row = mt * 32 + ms * 16 + l15;
          short8 afr = *(const short8*)(base + ((row * 512 + kc2) ^ ((row & 7) << 4)));
#pragma unroll
          for (int ns = 0; ns < 2; ++ns)
            acc[ms][ns] = __builtin_amdgcn_mfma_f32_16x16x32_bf16(afr, Bf[j][ns],
                                                                  acc[ms][ns], 0, 0, 0);
        }
      }
      if (c < 7) {                      // write-late into the other slot
        char* wb = (char*)Abuf[(c + 1) & 1];
#pragma unroll
        for (int p = 0; p < 4; ++p)
          *(short8*)(wb + ((row_st * 512 + koff * 2 + p * 16) ^ swzst)) = nx[p];
      }
      __syncthreads();
    }

    // ---- K-split partial dump (C layout: b=(lane>>4)*4+i, col=lane&15) ----
#pragma unroll
    for (int ms = 0; ms < 2; ++ms)
#pragma unroll
      for (int ns = 0; ns < 2; ++ns)
#pragma unroll
        for (int i = 0; i < 4; ++i)
          P_lds[ks][mt * 32 + ms * 16 + l4 * 4 + i][ns * 16 + l15] = acc[ms][ns][i];
    __syncthreads();

    // ---- gate math + state update ----
    float pr[4];
#pragma unroll
    for (int g4 = 0; g4 < 4; ++g4) {
      float s = brg[g4];
#pragma unroll
      for (int q = 0; q < 4; ++q) s += P_lds[q][gb][g4 * 8 + gnn];
      pr[g4] = s;
    }
    float ig = 1.0f / (1.0f + expf(-pr[0]));
    float og = 1.0f / (1.0f + expf(-pr[1]));
    float fg = 1.0f / (1.0f + expf(-pr[2]));
    float cg = tanhf(pr[3]);
    c_reg = fg * c_reg + ig * cg;
    pend_h = og * tanhf(c_reg);

    // prefetch next step's x-chunk0 (read-only; hides under gate math + barrier)
    if (t < T_SZ - 1) {
      int tok = tokens[(d ? (T_SZ - 2 - t) : (t + 1)) * B_SZ + row_st];
      const short* s = embT + (size_t)tok * 1024 + koff;
#pragma unroll
      for (int p = 0; p < 4; ++p) pre0[p] = *(const short8*)(s + p * 8);
    }

    hdst[gb * 1024 + gcol] = f2bf(pend_h);   // the only store the barrier must cover

    if (t < T_SZ - 1) {
      __syncthreads();   // all threads' h-stores drained (vmcnt(0)) -> in XCD L2
      if (tid == 0) {
        // release: device-scope fence = cache-wide L2 writeback, covers the
        // whole block's h-stores (already drained to L2 by the barrier above)
        __threadfence();
        __hip_atomic_fetch_add(cnt, 1u, __ATOMIC_RELAXED, __HIP_MEMORY_SCOPE_AGENT);
        const unsigned target = (unsigned)(t + 1) * 128u;  // 128 blocks per dir
        while (__hip_atomic_load(cnt, __ATOMIC_RELAXED, __HIP_MEMORY_SCOPE_AGENT) < target)
          __builtin_amdgcn_s_sleep(2);
        __threadfence();  // acquire: invalidate stale L1/L2 before reading peer h
      }
      __syncthreads();
    }
  }

  // final step's out-stores
  {
    size_t o = (size_t)(((T_SZ - 1) * B_SZ + gb)) * 2048 + (size_t)d * 1024 + gcol;
    out[o] = pend_h;
    out[o + 67108864] = c_reg;
  }
}

extern "C" void kernel_launch(void* const* d_in, const int* in_sizes, int n_in,
                              void* d_out, int out_size, void* d_ws, size_t ws_size,
                              hipStream_t stream) {
  (void)in_sizes; (void)n_in; (void)out_size; (void)ws_size;
  const int* tokens  = (const int*)d_in[0];
  const float* emb_w = (const float*)d_in[1];
  const float* emb_b = (const float*)d_in[2];

  char* ws = (char*)d_ws;
  short* embT   = (short*)(ws);               // 65,536,000 B
  short* Wbf    = (short*)(ws + 65536000);    // 33,554,432 B
  float* biasws = (float*)(ws + 99090432);    //     32,768 B
  short* hbf    = (short*)(ws + 99123200);    //    524,288 B (2 phase x 2 dir x 64x1024)
  unsigned* bar = (unsigned*)(ws + 99647488); //        512 B

  (void)hipMemsetAsync(ws + 99123200, 0, 524288 + 512, stream);

  k_embT<<<dim3(500, 16), 256, 0, stream>>>(emb_w, emb_b, embT);

  for (int d = 0; d < 2; ++d)
    for (int g = 0; g < 4; ++g) {
      const float* wsrc = (const float*)d_in[3 + d * 8 + g * 2];
      const float* bsrc = (const float*)d_in[4 + d * 8 + g * 2];
      k_cast<<<1024, 256, 0, stream>>>(wsrc, Wbf + (size_t)(d * 4 + g) * 1024 * 2048,
                                       1024 * 2048);
      k_copy<<<4, 256, 0, stream>>>(bsrc, biasws + (d * 4 + g) * 1024, 1024);
    }

  float* outp = (float*)d_out;
  void* kargs[] = {(void*)&tokens, (void*)&embT, (void*)&Wbf, (void*)&biasws,
                   (void*)&hbf, (void*)&bar, (void*)&outp};
  (void)hipLaunchCooperativeKernel((const void*)k_persist, dim3(256), dim3(512), kargs,
                                   0, stream);
}

// Round 5
// 9035.346 us; speedup vs baseline: 4.7651x; 1.6051x over previous
//
#include <hip/hip_runtime.h>
#include <cstdint>
#include <cstddef>

#define V_SZ 32000
#define H_SZ 1024
#define T_SZ 512
#define B_SZ 64

typedef short short8 __attribute__((ext_vector_type(8)));
typedef float f32x4 __attribute__((ext_vector_type(4)));
typedef unsigned long long u64;

__device__ __forceinline__ short f2bf(float f) {
  union { float f; unsigned u; } v; v.f = f;
  unsigned r = (v.u + 0x7fffu + ((v.u >> 16) & 1u)) >> 16;  // RNE, inputs finite
  return (short)r;
}

// coherent (per-access, no cache maintenance) 8B load / 2B store
__device__ __forceinline__ u64 cl8(const u64* p) {
  return __hip_atomic_load(p, __ATOMIC_RELAXED, __HIP_MEMORY_SCOPE_AGENT);
}
__device__ __forceinline__ void cs2(unsigned short* p, unsigned short v) {
  __hip_atomic_store(p, v, __ATOMIC_RELAXED, __HIP_MEMORY_SCOPE_AGENT);
}

// embT[v][h] = bf16(emb_w[h][v] + emb_b[h])  -- tiled transpose, both sides coalesced
__global__ __launch_bounds__(256) void k_embT(const float* __restrict__ emb_w,
                                              const float* __restrict__ emb_b,
                                              short* __restrict__ embT) {
  __shared__ float tile[64][65];
  const int v0 = blockIdx.x * 64, h0 = blockIdx.y * 64;
  const int c = threadIdx.x & 63, rg = threadIdx.x >> 6;
#pragma unroll
  for (int p = 0; p < 16; ++p) {
    int r = rg * 16 + p;
    tile[r][c] = emb_w[(size_t)(h0 + r) * V_SZ + v0 + c];
  }
  __syncthreads();
  const float bias = emb_b[h0 + c];
#pragma unroll
  for (int p = 0; p < 16; ++p) {
    int vr = rg * 16 + p;
    embT[(size_t)(v0 + vr) * H_SZ + h0 + c] = f2bf(tile[c][vr] + bias);
  }
}

__global__ __launch_bounds__(256) void k_cast(const float* __restrict__ s,
                                              short* __restrict__ d, int n) {
  for (int i = blockIdx.x * 256 + threadIdx.x; i < n; i += gridDim.x * 256)
    d[i] = f2bf(s[i]);
}

__global__ __launch_bounds__(256) void k_copy(const float* __restrict__ s,
                                              float* __restrict__ d, int n) {
  for (int i = blockIdx.x * 256 + threadIdx.x; i < n; i += gridDim.x * 256)
    d[i] = s[i];
}

// Persistent bidirectional LSTM. 256 blocks x 512 threads, 1 block/CU (LDS-capped).
// block: d = blockIdx>>7, n0 = (blockIdx&127)*8 output cols (x4 gates = 32 W-rows).
// wave w: mt = w>>2 (batch 32-half), ks = w&3 (K quarter, strided mod 4).
// Weights live in AGPRs (unified file) all 512 steps; c-state in a register.
// h-exchange: per-access coherent stores/loads (sc bits) -> NO fences anywhere.
__global__ __launch_bounds__(512) void k_persist(
    const int* __restrict__ tokens, const short* __restrict__ embT,
    const short* __restrict__ Wbf, const float* __restrict__ biasws,
    short* __restrict__ hbf, unsigned* __restrict__ bar,
    float* __restrict__ out) {
  __shared__ __align__(16) short Abuf[2][16384];   // ring-2: [64 rows][256 k] each
  __shared__ float P_lds[4][64][36];               // [ks][b][32 cols] pad->stride 36

  const int tid = threadIdx.x;
  const int lane = tid & 63, w = tid >> 6;
  const int l15 = lane & 15, l4 = lane >> 4;
  const int d = (int)(blockIdx.x >> 7);
  const int n0 = (int)(blockIdx.x & 127) << 3;
  const int mt = w >> 2, ks = w & 3;

  // staging map: thread owns row row_st, 64 contiguous bytes at koff*2
  const int row_st = tid >> 3;
  const int koff = (tid & 7) * 32;                 // elements within 256-chunk
  const int swzst = (row_st & 7) << 4;
  const int stbase = row_st * 512 + koff * 2;      // byte offset in slot

  // ---- load step-invariant B fragments (compiler places in AGPRs) ----
  short8 Bf[16][2];
#pragma unroll
  for (int j = 0; j < 16; ++j)
#pragma unroll
    for (int nt = 0; nt < 2; ++nt) {
      int row32 = nt * 16 + l15;
      size_t grow = (size_t)((d * 4 + (row32 >> 3)) * 1024 + n0 + (row32 & 7));
      Bf[j][nt] = *(const short8*)(Wbf + grow * 2048 + (j * 4 + ks) * 32 + l4 * 8);
    }

  // ---- gate-phase constants: thread owns (b=tid>>3, col=n0+(tid&7)) ----
  const int gb = tid >> 3, gnn = tid & 7, gcol = n0 + gnn;
  float brg[4];
#pragma unroll
  for (int g4 = 0; g4 < 4; ++g4) brg[g4] = biasws[d * 4096 + g4 * 1024 + gcol];
  float c_reg = 0.f;
  float pend_h = 0.f;

  unsigned* const cnt = bar + d * 64;  // per-dir counter, 256B apart

#define ISSUE_X(dst, cn)                                                      \
  do { _Pragma("unroll")                                                      \
    for (int p_ = 0; p_ < 4; ++p_)                                            \
      dst[p_] = *(const short8*)(xbase + (cn) * 256 + p_ * 8);                \
  } while (0)

#define ISSUE_H(dst, cn)                                                      \
  do { const u64* hp_ = (const u64*)(hsrc + row_st * 1024 + ((cn)-4) * 256 + koff); \
    _Pragma("unroll")                                                         \
    for (int i_ = 0; i_ < 8; ++i_) dst[i_] = cl8(hp_ + i_);                   \
  } while (0)

#define STORE_X(src, cn)                                                      \
  do { char* wb_ = (char*)Abuf[(cn) & 1];                                     \
    _Pragma("unroll")                                                         \
    for (int p_ = 0; p_ < 4; ++p_)                                            \
      *(short8*)(wb_ + ((stbase + p_ * 16) ^ swzst)) = src[p_];               \
  } while (0)

#define STORE_H(src, cn)                                                      \
  do { char* wb_ = (char*)Abuf[(cn) & 1];                                     \
    _Pragma("unroll")                                                         \
    for (int i_ = 0; i_ < 8; ++i_)                                            \
      *(u64*)(wb_ + ((stbase + i_ * 8) ^ swzst)) = src[i_];                   \
  } while (0)

#define MFMA_CHUNK(SLOT, J0)                                                  \
  do { const char* base_ = (const char*)Abuf[SLOT];                           \
    _Pragma("unroll")                                                         \
    for (int j2_ = 0; j2_ < 2; ++j2_) {                                       \
      const int kc2_ = ((j2_ * 4 + ks) * 32 + l4 * 8) * 2;                    \
      _Pragma("unroll")                                                       \
      for (int ms_ = 0; ms_ < 2; ++ms_) {                                     \
        int row_ = mt * 32 + ms_ * 16 + l15;                                  \
        short8 afr_ = *(const short8*)(base_ + ((row_ * 512 + kc2_) ^ ((row_ & 7) << 4))); \
        _Pragma("unroll")                                                     \
        for (int ns_ = 0; ns_ < 2; ++ns_)                                     \
          acc[ms_][ns_] = __builtin_amdgcn_mfma_f32_16x16x32_bf16(            \
              afr_, Bf[(J0) + j2_][ns_], acc[ms_][ns_], 0, 0, 0);             \
      }                                                                       \
    }                                                                         \
  } while (0)

  for (int t = 0; t < T_SZ; ++t) {
    const int td = d ? (T_SZ - 1 - t) : t;
    const short* hsrc = hbf + ((t & 1) * 2 + d) * 65536;
    short* hdst = hbf + (((t + 1) & 1) * 2 + d) * 65536;
    const int tok = tokens[td * B_SZ + row_st];
    const short* xbase = embT + (size_t)tok * 1024 + koff;

    // issue in CONSUMPTION ORDER (vmcnt retires in order): x0..x3 then h4,h5
    short8 x0r[4], x1r[4], x2r[4], x3r[4];
    u64 hA[8], hB[8], hC[8], hD[8];
    ISSUE_X(x0r, 0);
    ISSUE_X(x1r, 1);
    ISSUE_X(x2r, 2);
    ISSUE_X(x3r, 3);
    ISSUE_H(hA, 4);
    ISSUE_H(hB, 5);

    // deferred out-stores for step t-1 (overlap with staging latency)
    if (t > 0) {
      size_t o = (size_t)(((t - 1) * B_SZ + gb)) * 2048 + (size_t)d * 1024 + gcol;
      out[o] = pend_h;
      out[o + 67108864] = c_reg;
    }

    STORE_X(x0r, 0);
    __syncthreads();

    f32x4 acc[2][2] = {{{0,0,0,0},{0,0,0,0}},{{0,0,0,0},{0,0,0,0}}};

    MFMA_CHUNK(0, 0);  STORE_X(x1r, 1); __syncthreads();
    MFMA_CHUNK(1, 2);  STORE_X(x2r, 2); __syncthreads();
    MFMA_CHUNK(0, 4);  STORE_X(x3r, 3); __syncthreads();
    ISSUE_H(hC, 6);
    MFMA_CHUNK(1, 6);  STORE_H(hA, 4);  __syncthreads();
    ISSUE_H(hD, 7);
    MFMA_CHUNK(0, 8);  STORE_H(hB, 5);  __syncthreads();
    MFMA_CHUNK(1, 10); STORE_H(hC, 6);  __syncthreads();
    MFMA_CHUNK(0, 12); STORE_H(hD, 7);  __syncthreads();
    MFMA_CHUNK(1, 14);

    // ---- K-split partial dump (C layout: b=(lane>>4)*4+i, col=lane&15) ----
#pragma unroll
    for (int ms = 0; ms < 2; ++ms)
#pragma unroll
      for (int ns = 0; ns < 2; ++ns)
#pragma unroll
        for (int i = 0; i < 4; ++i)
          P_lds[ks][mt * 32 + ms * 16 + l4 * 4 + i][ns * 16 + l15] = acc[ms][ns][i];
    __syncthreads();

    // ---- gate math + state update ----
    float pr[4];
#pragma unroll
    for (int g4 = 0; g4 < 4; ++g4) {
      float s = brg[g4];
#pragma unroll
      for (int q = 0; q < 4; ++q) s += P_lds[q][gb][g4 * 8 + gnn];
      pr[g4] = s;
    }
    float ig = 1.0f / (1.0f + expf(-pr[0]));
    float og = 1.0f / (1.0f + expf(-pr[1]));
    float fg = 1.0f / (1.0f + expf(-pr[2]));
    float cg = tanhf(pr[3]);
    c_reg = fg * c_reg + ig * cg;
    pend_h = og * tanhf(c_reg);

    // coherent h publish (write-through to coherence point; no cache flush needed)
    cs2((unsigned short*)&hdst[gb * 1024 + gcol], (unsigned short)f2bf(pend_h));

    if (t < T_SZ - 1) {
      __syncthreads();   // each wave's s_waitcnt vmcnt(0) drains its coherent stores
      if (tid == 0) {
        __hip_atomic_fetch_add(cnt, 1u, __ATOMIC_RELAXED, __HIP_MEMORY_SCOPE_AGENT);
        const unsigned target = (unsigned)(t + 1) * 128u;  // 128 blocks per dir
        while (__hip_atomic_load(cnt, __ATOMIC_RELAXED, __HIP_MEMORY_SCOPE_AGENT) < target)
          __builtin_amdgcn_s_sleep(4);
      }
      __syncthreads();
    }
  }

  // final step's out-stores
  {
    size_t o = (size_t)(((T_SZ - 1) * B_SZ + gb)) * 2048 + (size_t)d * 1024 + gcol;
    out[o] = pend_h;
    out[o + 67108864] = c_reg;
  }
#undef ISSUE_X
#undef ISSUE_H
#undef STORE_X
#undef STORE_H
#undef MFMA_CHUNK
}

extern "C" void kernel_launch(void* const* d_in, const int* in_sizes, int n_in,
                              void* d_out, int out_size, void* d_ws, size_t ws_size,
                              hipStream_t stream) {
  (void)in_sizes; (void)n_in; (void)out_size; (void)ws_size;
  const int* tokens  = (const int*)d_in[0];
  const float* emb_w = (const float*)d_in[1];
  const float* emb_b = (const float*)d_in[2];

  char* ws = (char*)d_ws;
  short* embT   = (short*)(ws);               // 65,536,000 B
  short* Wbf    = (short*)(ws + 65536000);    // 33,554,432 B
  float* biasws = (float*)(ws + 99090432);    //     32,768 B
  short* hbf    = (short*)(ws + 99123200);    //    524,288 B (2 phase x 2 dir x 64x1024)
  unsigned* bar = (unsigned*)(ws + 99647488); //        512 B

  (void)hipMemsetAsync(ws + 99123200, 0, 524288 + 512, stream);

  k_embT<<<dim3(500, 16), 256, 0, stream>>>(emb_w, emb_b, embT);

  for (int d = 0; d < 2; ++d)
    for (int g = 0; g < 4; ++g) {
      const float* wsrc = (const float*)d_in[3 + d * 8 + g * 2];
      const float* bsrc = (const float*)d_in[4 + d * 8 + g * 2];
      k_cast<<<1024, 256, 0, stream>>>(wsrc, Wbf + (size_t)(d * 4 + g) * 1024 * 2048,
                                       1024 * 2048);
      k_copy<<<4, 256, 0, stream>>>(bsrc, biasws + (d * 4 + g) * 1024, 1024);
    }

  float* outp = (float*)d_out;
  void* kargs[] = {(void*)&tokens, (void*)&embT, (void*)&Wbf, (void*)&biasws,
                   (void*)&hbf, (void*)&bar, (void*)&outp};
  (void)hipLaunchCooperativeKernel((const void*)k_persist, dim3(256), dim3(512), kargs,
                                   0, stream);
}

// Round 7
// 6693.805 us; speedup vs baseline: 6.4320x; 1.3498x over previous
//
#include <hip/hip_runtime.h>
#include <cstdint>
#include <cstddef>

#define V_SZ 32000
#define H_SZ 1024
#define T_SZ 512
#define B_SZ 64

typedef short short8 __attribute__((ext_vector_type(8)));
typedef float f32x4 __attribute__((ext_vector_type(4)));
typedef unsigned long long u64;

__device__ __forceinline__ short f2bf(float f) {
  union { float f; unsigned u; } v; v.f = f;
  unsigned r = (v.u + 0x7fffu + ((v.u >> 16) & 1u)) >> 16;  // RNE, inputs finite
  return (short)r;
}

// coherent (per-access, no cache maintenance) 8B load / 2B store
__device__ __forceinline__ u64 cl8(const u64* p) {
  return __hip_atomic_load(p, __ATOMIC_RELAXED, __HIP_MEMORY_SCOPE_AGENT);
}
__device__ __forceinline__ void cs2(unsigned short* p, unsigned short v) {
  __hip_atomic_store(p, v, __ATOMIC_RELAXED, __HIP_MEMORY_SCOPE_AGENT);
}

// embT[v][h] = bf16(emb_w[h][v] + emb_b[h])  -- tiled transpose, both sides coalesced
__global__ __launch_bounds__(256) void k_embT(const float* __restrict__ emb_w,
                                              const float* __restrict__ emb_b,
                                              short* __restrict__ embT) {
  __shared__ float tile[64][65];
  const int v0 = blockIdx.x * 64, h0 = blockIdx.y * 64;
  const int c = threadIdx.x & 63, rg = threadIdx.x >> 6;
#pragma unroll
  for (int p = 0; p < 16; ++p) {
    int r = rg * 16 + p;
    tile[r][c] = emb_w[(size_t)(h0 + r) * V_SZ + v0 + c];
  }
  __syncthreads();
  const float bias = emb_b[h0 + c];
#pragma unroll
  for (int p = 0; p < 16; ++p) {
    int vr = rg * 16 + p;
    embT[(size_t)(v0 + vr) * H_SZ + h0 + c] = f2bf(tile[c][vr] + bias);
  }
}

__global__ __launch_bounds__(256) void k_cast(const float* __restrict__ s,
                                              short* __restrict__ d, int n) {
  for (int i = blockIdx.x * 256 + threadIdx.x; i < n; i += gridDim.x * 256)
    d[i] = f2bf(s[i]);
}

__global__ __launch_bounds__(256) void k_copy(const float* __restrict__ s,
                                              float* __restrict__ d, int n) {
  for (int i = blockIdx.x * 256 + threadIdx.x; i < n; i += gridDim.x * 256)
    d[i] = s[i];
}

// Persistent bidirectional LSTM. 256 blocks x 512 threads, 1 block/CU.
// block: d = blockIdx>>7, n0 = (blockIdx&127)*8 output cols (x4 gates = 32 W-rows).
// wave w: mt = w>>2 (batch 32-half), ks = w&3 (K quarter, strided mod 4).
// NO A-tile LDS staging (waves PARTITION A): fragments load straight from
// global into MFMA operand registers. Weights in registers; c-state in register.
// Barrier: hierarchical (8 groups x 16 + root), overlapped with next step's
// x-half (token-dependent only).
__global__ __launch_bounds__(512, 2) void k_persist(
    const int* __restrict__ tokens, const short* __restrict__ embT,
    const short* __restrict__ Wbf, const float* __restrict__ biasws,
    short* __restrict__ hbf, unsigned* __restrict__ bar,
    float* __restrict__ out) {
  __shared__ float P_lds[4][64][36];  // [ks][b][32 cols] pad->stride 36

  const int tid = threadIdx.x;
  const int lane = tid & 63, w = tid >> 6;
  const int l15 = lane & 15, l4 = lane >> 4;
  const int d = (int)(blockIdx.x >> 7);
  const int bflat = (int)(blockIdx.x & 127);
  const int n0 = bflat << 3;
  const int mt = w >> 2, ks = w & 3;
  const int rowA0 = mt * 32 + l15;          // ms=0 fragment row; ms=1 adds 16
  const int kfoff = ks * 32 + l4 * 8;       // within-slab-group k offset (elements)

  // ---- step-invariant B fragments in registers (slab j*4+ks, j=0..15) ----
  short8 Bf[16][2];
#pragma unroll
  for (int j = 0; j < 16; ++j)
#pragma unroll
    for (int nt = 0; nt < 2; ++nt) {
      int row32 = nt * 16 + l15;
      size_t grow = (size_t)((d * 4 + (row32 >> 3)) * 1024 + n0 + (row32 & 7));
      Bf[j][nt] = *(const short8*)(Wbf + grow * 2048 + (j * 4 + ks) * 32 + l4 * 8);
    }

  // ---- gate-phase constants: thread owns (b=tid>>3, col=n0+(tid&7)) ----
  const int gb = tid >> 3, gnn = tid & 7, gcol = n0 + gnn;
  float brg[4];
#pragma unroll
  for (int g4 = 0; g4 < 4; ++g4) brg[g4] = biasws[d * 4096 + g4 * 1024 + gcol];
  float c_reg = 0.f;

  // ---- hierarchical barrier pointers (64B-spaced lines) ----
  const int grp = bflat >> 4;                       // 0..7 (16 blocks each)
  unsigned* const grpc = bar + 32 + (d * 8 + grp) * 16;
  unsigned* const root = bar + d * 16;

  const f32x4 fzero = {0.f, 0.f, 0.f, 0.f};
  f32x4 acc[2][2];

  // x-half of step s: direct-to-frag cached loads from embT, 32 MFMA.
  // Runs BETWEEN arrive(s-1) and spin(s-1): depends only on tokens, not h.
  auto X_PHASE = [&](int s) {
    const int td = d ? (T_SZ - 1 - s) : s;
    const short* xb0 = embT + (size_t)tokens[td * B_SZ + rowA0] * 1024 + kfoff;
    const short* xb1 = embT + (size_t)tokens[td * B_SZ + rowA0 + 16] * 1024 + kfoff;
    short8 xf[8][2];
#pragma unroll
    for (int j = 0; j < 8; ++j) {
      xf[j][0] = *(const short8*)(xb0 + j * 128);
      xf[j][1] = *(const short8*)(xb1 + j * 128);
    }
#pragma unroll
    for (int ms = 0; ms < 2; ++ms)
#pragma unroll
      for (int ns = 0; ns < 2; ++ns) acc[ms][ns] = fzero;
#pragma unroll
    for (int j = 0; j < 8; ++j)
#pragma unroll
      for (int ms = 0; ms < 2; ++ms)
#pragma unroll
        for (int ns = 0; ns < 2; ++ns)
          acc[ms][ns] = __builtin_amdgcn_mfma_f32_16x16x32_bf16(
              xf[j][ms], Bf[j][ns], acc[ms][ns], 0, 0, 0);
  };

  X_PHASE(0);  // prologue: x-half of step 0

  for (int t = 0; t < T_SZ; ++t) {
    const short* hsrc = hbf + ((t & 1) * 2 + d) * 65536;
    short* hdst = hbf + (((t + 1) & 1) * 2 + d) * 65536;

    // ---- h-half: coherent direct-to-frag loads (issue all 32, then MFMA) ----
    // slab j covers h-elements [j*128 + kfoff, +8) => u64 offset j*32 (+1)
    union HQ { u64 q[2]; short8 s; } hf[8][2];
    {
      const u64* p0 = (const u64*)(hsrc + rowA0 * 1024 + kfoff);
      const u64* p1 = (const u64*)(hsrc + (rowA0 + 16) * 1024 + kfoff);
#pragma unroll
      for (int j = 0; j < 8; ++j) {
        hf[j][0].q[0] = cl8(p0 + j * 32);
        hf[j][0].q[1] = cl8(p0 + j * 32 + 1);
        hf[j][1].q[0] = cl8(p1 + j * 32);
        hf[j][1].q[1] = cl8(p1 + j * 32 + 1);
      }
    }
#pragma unroll
    for (int j = 0; j < 8; ++j)
#pragma unroll
      for (int ms = 0; ms < 2; ++ms)
#pragma unroll
        for (int ns = 0; ns < 2; ++ns)
          acc[ms][ns] = __builtin_amdgcn_mfma_f32_16x16x32_bf16(
              hf[j][ms].s, Bf[8 + j][ns], acc[ms][ns], 0, 0, 0);

    // ---- K-split partial dump (C layout: b=(lane>>4)*4+i, col=lane&15) ----
#pragma unroll
    for (int ms = 0; ms < 2; ++ms)
#pragma unroll
      for (int ns = 0; ns < 2; ++ns)
#pragma unroll
        for (int i = 0; i < 4; ++i)
          P_lds[ks][mt * 32 + ms * 16 + l4 * 4 + i][ns * 16 + l15] = acc[ms][ns][i];
    __syncthreads();

    // ---- gate math + state update ----
    float pr[4];
#pragma unroll
    for (int g4 = 0; g4 < 4; ++g4) {
      float s = brg[g4];
#pragma unroll
      for (int q = 0; q < 4; ++q) s += P_lds[q][gb][g4 * 8 + gnn];
      pr[g4] = s;
    }
    float ig = 1.0f / (1.0f + expf(-pr[0]));
    float og = 1.0f / (1.0f + expf(-pr[1]));
    float fg = 1.0f / (1.0f + expf(-pr[2]));
    float cg = tanhf(pr[3]);
    c_reg = fg * c_reg + ig * cg;
    float hnew = og * tanhf(c_reg);

    // coherent h publish + output stores (all drained by the next barrier)
    cs2((unsigned short*)&hdst[gb * 1024 + gcol], (unsigned short)f2bf(hnew));
    size_t o = (size_t)(t * B_SZ + gb) * 2048 + (size_t)d * 1024 + gcol;
    out[o] = hnew;
    out[o + 67108864] = c_reg;

    __syncthreads();  // drain stores (vmcnt 0 per wave); also guards P_lds reuse

    if (t < T_SZ - 1) {
      if (tid == 0) {  // arrive: group counter, last-of-group bumps root
        unsigned old = __hip_atomic_fetch_add(grpc, 1u, __ATOMIC_RELAXED,
                                              __HIP_MEMORY_SCOPE_AGENT);
        if (old == (unsigned)((t + 1) * 16 - 1))
          __hip_atomic_fetch_add(root, 1u, __ATOMIC_RELAXED,
                                 __HIP_MEMORY_SCOPE_AGENT);
      }
      X_PHASE(t + 1);  // overlap barrier latency with next step's x-half
      if (tid == 0) {
        const unsigned tgt = (unsigned)((t + 1) * 8);
        while (__hip_atomic_load(root, __ATOMIC_RELAXED,
                                 __HIP_MEMORY_SCOPE_AGENT) < tgt)
          __builtin_amdgcn_s_sleep(2);
      }
      __syncthreads();
    }
  }
}

extern "C" void kernel_launch(void* const* d_in, const int* in_sizes, int n_in,
                              void* d_out, int out_size, void* d_ws, size_t ws_size,
                              hipStream_t stream) {
  (void)in_sizes; (void)n_in; (void)out_size; (void)ws_size;
  const int* tokens  = (const int*)d_in[0];
  const float* emb_w = (const float*)d_in[1];
  const float* emb_b = (const float*)d_in[2];

  char* ws = (char*)d_ws;
  short* embT   = (short*)(ws);               // 65,536,000 B
  short* Wbf    = (short*)(ws + 65536000);    // 33,554,432 B
  float* biasws = (float*)(ws + 99090432);    //     32,768 B
  short* hbf    = (short*)(ws + 99123200);    //    524,288 B (2 phase x 2 dir x 64x1024)
  unsigned* bar = (unsigned*)(ws + 99647488); //      2,048 B

  (void)hipMemsetAsync(ws + 99123200, 0, 524288 + 2048, stream);

  k_embT<<<dim3(500, 16), 256, 0, stream>>>(emb_w, emb_b, embT);

  for (int d = 0; d < 2; ++d)
    for (int g = 0; g < 4; ++g) {
      const float* wsrc = (const float*)d_in[3 + d * 8 + g * 2];
      const float* bsrc = (const float*)d_in[4 + d * 8 + g * 2];
      k_cast<<<1024, 256, 0, stream>>>(wsrc, Wbf + (size_t)(d * 4 + g) * 1024 * 2048,
                                       1024 * 2048);
      k_copy<<<4, 256, 0, stream>>>(bsrc, biasws + (d * 4 + g) * 1024, 1024);
    }

  float* outp = (float*)d_out;
  void* kargs[] = {(void*)&tokens, (void*)&embT, (void*)&Wbf, (void*)&biasws,
                   (void*)&hbf, (void*)&bar, (void*)&outp};
  (void)hipLaunchCooperativeKernel((const void*)k_persist, dim3(256), dim3(512), kargs,
                                   0, stream);
}

// Round 9
// 3335.244 us; speedup vs baseline: 12.9089x; 2.0070x over previous
//
#include <hip/hip_runtime.h>
#include <cstdint>
#include <cstddef>

#define V_SZ 32000
#define H_SZ 1024
#define T_SZ 512
#define B_SZ 64

typedef short short8 __attribute__((ext_vector_type(8)));
typedef float f32x4 __attribute__((ext_vector_type(4)));
typedef unsigned long long u64;

__device__ __forceinline__ short f2bf(float f) {
  union { float f; unsigned u; } v; v.f = f;
  unsigned r = (v.u + 0x7fffu + ((v.u >> 16) & 1u)) >> 16;  // RNE, inputs finite
  return (short)r;
}

__device__ __forceinline__ void cs8(u64* p, u64 v) {
  __hip_atomic_store(p, v, __ATOMIC_RELAXED, __HIP_MEMORY_SCOPE_AGENT);
}

// embT[v][h] = bf16(emb_w[h][v] + emb_b[h])  -- tiled transpose, both sides coalesced
__global__ __launch_bounds__(256) void k_embT(const float* __restrict__ emb_w,
                                              const float* __restrict__ emb_b,
                                              short* __restrict__ embT) {
  __shared__ float tile[64][65];
  const int v0 = blockIdx.x * 64, h0 = blockIdx.y * 64;
  const int c = threadIdx.x & 63, rg = threadIdx.x >> 6;
#pragma unroll
  for (int p = 0; p < 16; ++p) {
    int r = rg * 16 + p;
    tile[r][c] = emb_w[(size_t)(h0 + r) * V_SZ + v0 + c];
  }
  __syncthreads();
  const float bias = emb_b[h0 + c];
#pragma unroll
  for (int p = 0; p < 16; ++p) {
    int vr = rg * 16 + p;
    embT[(size_t)(v0 + vr) * H_SZ + h0 + c] = f2bf(tile[c][vr] + bias);
  }
}

__global__ __launch_bounds__(256) void k_cast(const float* __restrict__ s,
                                              short* __restrict__ d, int n) {
  for (int i = blockIdx.x * 256 + threadIdx.x; i < n; i += gridDim.x * 256)
    d[i] = f2bf(s[i]);
}

__global__ __launch_bounds__(256) void k_copy(const float* __restrict__ s,
                                              float* __restrict__ d, int n) {
  for (int i = blockIdx.x * 256 + threadIdx.x; i < n; i += gridDim.x * 256)
    d[i] = s[i];
}

// Persistent bidirectional LSTM. 256 blocks x 512 threads, 1 block/CU.
// Retile: block = (32 batch rows) x (16 cols x 4 gates = 64 W-rows);
//   d = bid>>7; bg = (bid&127)>>6 (2 batch halves); cg = bid&63; n0 = cg*16.
// Coherent-h traffic/dir = 64*(1024/cols)*2KB -> cols 8->16 halves it (16 MB/step).
// wave w owns K-slabs {j : j%8==w} (4 x-slabs + 4 h-slabs, balanced for overlap).
// Weights (Bf[8][4] = 128 regs) live in registers all 512 steps; c-state in reg.
// h loads: 16B asm global_load_dwordx4 sc0 sc1 (4x fewer fabric requests than 8B),
// outputs EARLY-CLOBBER (=&v) so they can't alias the live pointer inputs.
// Barrier: hierarchical (8 groups x 16 + root), overlapped with next step's x-half.
__global__ __launch_bounds__(512, 2) void k_persist(
    const int* __restrict__ tokens, const short* __restrict__ embT,
    const short* __restrict__ Wbf, const float* __restrict__ biasws,
    short* __restrict__ hbf, unsigned* __restrict__ bar,
    float* __restrict__ out) {
  __shared__ float P_lds[8][32][68];   // [K-eighth][b32][64 cols + 4 pad]
  __shared__ short h_sh[32][16];       // publish repack buffer

  const int tid = threadIdx.x;
  const int lane = tid & 63, w = tid >> 6;
  const int l15 = lane & 15, l4 = lane >> 4;
  const int d = (int)(blockIdx.x >> 7);
  const int bflat = (int)(blockIdx.x & 127);
  const int bg = bflat >> 6;                 // 0..1 batch half
  const int cg = bflat & 63;                 // 0..63 col group
  const int n0 = cg << 4;
  const int r0 = bg * 32 + l15, r1 = r0 + 16;  // A-fragment batch rows (ms=0/1)
  const int kw = w * 32 + l4 * 8;              // lane k-base (slab w, quarter l4)

  // ---- step-invariant B fragments in registers: slab w+jj*8, N-tile nt ----
  short8 Bf[8][4];
#pragma unroll
  for (int jj = 0; jj < 8; ++jj) {
    int slab = w + jj * 8;
#pragma unroll
    for (int nt = 0; nt < 4; ++nt) {
      int row64 = nt * 16 + l15;             // flat (gate,col) 0..63
      size_t grow = (size_t)((d * 4 + (row64 >> 4)) * 1024 + n0 + (row64 & 15));
      Bf[jj][nt] = *(const short8*)(Wbf + grow * 2048 + slab * 32 + l4 * 8);
    }
  }

  // ---- gate-phase constants: thread owns (b32=tid>>4, c16=tid&15) ----
  const int b32 = tid >> 4, c16 = tid & 15;
  const int gcol = n0 + c16, gbrow = bg * 32 + b32;
  float brg[4];
#pragma unroll
  for (int g4 = 0; g4 < 4; ++g4) brg[g4] = biasws[d * 4096 + g4 * 1024 + gcol];
  float c_reg = 0.f;

  // ---- hierarchical barrier pointers (64B-spaced lines) ----
  const int grp = bflat >> 4;                // 0..7 (16 blocks each)
  unsigned* const grpc = bar + 32 + (d * 8 + grp) * 16;
  unsigned* const root = bar + d * 16;

  const f32x4 fzero = {0.f, 0.f, 0.f, 0.f};
  f32x4 acc[2][4];

  // x-half of step s (token-dependent only): cached direct-to-frag + 32 MFMA.
  auto X_PHASE = [&](int s) {
    const int td = d ? (T_SZ - 1 - s) : s;
    const short* xb0 = embT + (size_t)tokens[td * B_SZ + r0] * 1024 + kw;
    const short* xb1 = embT + (size_t)tokens[td * B_SZ + r1] * 1024 + kw;
    short8 xf[2][4];
#pragma unroll
    for (int jj = 0; jj < 4; ++jj) {         // slab w+jj*8 -> +jj*256 elements
      xf[0][jj] = *(const short8*)(xb0 + jj * 256);
      xf[1][jj] = *(const short8*)(xb1 + jj * 256);
    }
#pragma unroll
    for (int ms = 0; ms < 2; ++ms)
#pragma unroll
      for (int nt = 0; nt < 4; ++nt) acc[ms][nt] = fzero;
#pragma unroll
    for (int jj = 0; jj < 4; ++jj)
#pragma unroll
      for (int ms = 0; ms < 2; ++ms)
#pragma unroll
        for (int nt = 0; nt < 4; ++nt)
          acc[ms][nt] = __builtin_amdgcn_mfma_f32_16x16x32_bf16(
              xf[ms][jj], Bf[jj][nt], acc[ms][nt], 0, 0, 0);
  };

  X_PHASE(0);  // prologue

  for (int t = 0; t < T_SZ; ++t) {
    const short* hsrc = hbf + ((t & 1) * 2 + d) * 65536;
    short* hdst = hbf + (((t + 1) & 1) * 2 + d) * 65536;

    // ---- h-half: coherent 16B fragment loads (one asm blob, FIFO-safe) ----
    // slab w+(4+q)*8 -> h-elem offset q*256 -> byte offset q*512 from base.
    // Outputs are EARLY-CLOBBER: they must not alias the pointer inputs.
    short8 hf[2][4];
    {
      const short* hb0 = hsrc + r0 * 1024 + kw;
      const short* hb1 = hsrc + r1 * 1024 + kw;
      asm volatile(
          "global_load_dwordx4 %0, %8, off sc0 sc1\n\t"
          "global_load_dwordx4 %1, %8, off offset:512 sc0 sc1\n\t"
          "global_load_dwordx4 %2, %8, off offset:1024 sc0 sc1\n\t"
          "global_load_dwordx4 %3, %8, off offset:1536 sc0 sc1\n\t"
          "global_load_dwordx4 %4, %9, off sc0 sc1\n\t"
          "global_load_dwordx4 %5, %9, off offset:512 sc0 sc1\n\t"
          "global_load_dwordx4 %6, %9, off offset:1024 sc0 sc1\n\t"
          "global_load_dwordx4 %7, %9, off offset:1536 sc0 sc1\n\t"
          "s_waitcnt vmcnt(0)"
          : "=&v"(hf[0][0]), "=&v"(hf[0][1]), "=&v"(hf[0][2]), "=&v"(hf[0][3]),
            "=&v"(hf[1][0]), "=&v"(hf[1][1]), "=&v"(hf[1][2]), "=&v"(hf[1][3])
          : "v"(hb0), "v"(hb1)
          : "memory");
    }
#pragma unroll
    for (int jj = 0; jj < 4; ++jj)
#pragma unroll
      for (int ms = 0; ms < 2; ++ms)
#pragma unroll
        for (int nt = 0; nt < 4; ++nt)
          acc[ms][nt] = __builtin_amdgcn_mfma_f32_16x16x32_bf16(
              hf[ms][jj], Bf[4 + jj][nt], acc[ms][nt], 0, 0, 0);

    // ---- K-split partial dump (C layout: row=l4*4+i, col=l15) ----
#pragma unroll
    for (int ms = 0; ms < 2; ++ms)
#pragma unroll
      for (int nt = 0; nt < 4; ++nt)
#pragma unroll
        for (int i = 0; i < 4; ++i)
          P_lds[w][ms * 16 + l4 * 4 + i][nt * 16 + l15] = acc[ms][nt][i];
    __syncthreads();

    // ---- gate math + state update (thread: b32, c16) ----
    float pr[4];
#pragma unroll
    for (int g4 = 0; g4 < 4; ++g4) {
      float s = brg[g4];
#pragma unroll
      for (int q = 0; q < 8; ++q) s += P_lds[q][b32][g4 * 16 + c16];
      pr[g4] = s;
    }
    float ig = 1.0f / (1.0f + expf(-pr[0]));
    float og = 1.0f / (1.0f + expf(-pr[1]));
    float fg = 1.0f / (1.0f + expf(-pr[2]));
    float cg4 = tanhf(pr[3]);
    c_reg = fg * c_reg + ig * cg4;
    float hnew = og * tanhf(c_reg);

    // output stores (plain cached, off critical path)
    size_t o = (size_t)(t * B_SZ + gbrow) * 2048 + (size_t)d * 1024 + gcol;
    out[o] = hnew;
    out[o + 67108864] = c_reg;

    if (t < T_SZ - 1) {
      h_sh[b32][c16] = f2bf(hnew);
      __syncthreads();                       // h_sh visible
      if (tid < 128) {                       // repacked 8B coherent publish
        int r = tid >> 2, qq = tid & 3;
        cs8((u64*)(hdst + (bg * 32 + r) * 1024 + n0 + qq * 4),
            *(const u64*)&h_sh[r][qq * 4]);
      }
      __syncthreads();                       // publish drained (per-wave vmcnt 0)
      if (tid == 0) {                        // arrive
        unsigned old = __hip_atomic_fetch_add(grpc, 1u, __ATOMIC_RELAXED,
                                              __HIP_MEMORY_SCOPE_AGENT);
        if (old == (unsigned)((t + 1) * 16 - 1))
          __hip_atomic_fetch_add(root, 1u, __ATOMIC_RELAXED,
                                 __HIP_MEMORY_SCOPE_AGENT);
      }
      X_PHASE(t + 1);                        // overlap barrier with next x-half
      if (tid == 0) {
        const unsigned tgt = (unsigned)((t + 1) * 8);
        while (__hip_atomic_load(root, __ATOMIC_RELAXED,
                                 __HIP_MEMORY_SCOPE_AGENT) < tgt)
          __builtin_amdgcn_s_sleep(2);
      }
      __syncthreads();
    }
  }
}

extern "C" void kernel_launch(void* const* d_in, const int* in_sizes, int n_in,
                              void* d_out, int out_size, void* d_ws, size_t ws_size,
                              hipStream_t stream) {
  (void)in_sizes; (void)n_in; (void)out_size; (void)ws_size;
  const int* tokens  = (const int*)d_in[0];
  const float* emb_w = (const float*)d_in[1];
  const float* emb_b = (const float*)d_in[2];

  char* ws = (char*)d_ws;
  short* embT   = (short*)(ws);               // 65,536,000 B
  short* Wbf    = (short*)(ws + 65536000);    // 33,554,432 B
  float* biasws = (float*)(ws + 99090432);    //     32,768 B
  short* hbf    = (short*)(ws + 99123200);    //    524,288 B (2 phase x 2 dir x 64x1024)
  unsigned* bar = (unsigned*)(ws + 99647488); //      2,048 B

  (void)hipMemsetAsync(ws + 99123200, 0, 524288 + 2048, stream);

  k_embT<<<dim3(500, 16), 256, 0, stream>>>(emb_w, emb_b, embT);

  for (int d = 0; d < 2; ++d)
    for (int g = 0; g < 4; ++g) {
      const float* wsrc = (const float*)d_in[3 + d * 8 + g * 2];
      const float* bsrc = (const float*)d_in[4 + d * 8 + g * 2];
      k_cast<<<1024, 256, 0, stream>>>(wsrc, Wbf + (size_t)(d * 4 + g) * 1024 * 2048,
                                       1024 * 2048);
      k_copy<<<4, 256, 0, stream>>>(bsrc, biasws + (d * 4 + g) * 1024, 1024);
    }

  float* outp = (float*)d_out;
  void* kargs[] = {(void*)&tokens, (void*)&embT, (void*)&Wbf, (void*)&biasws,
                   (void*)&hbf, (void*)&bar, (void*)&outp};
  (void)hipLaunchCooperativeKernel((const void*)k_persist, dim3(256), dim3(512), kargs,
                                   0, stream);
}